// Round 10
// baseline (2722.265 us; speedup 1.0000x reference)
//
#include <hip/hip_runtime.h>
#include <cstdint>

typedef _Float16 f16;
typedef __attribute__((ext_vector_type(2))) _Float16 f16x2;
typedef __attribute__((ext_vector_type(8))) _Float16 f16x8;
typedef __attribute__((ext_vector_type(4))) float f32x4;
typedef __attribute__((ext_vector_type(2))) float f32x2;
typedef __attribute__((ext_vector_type(8))) unsigned short us8;   // 16 B — staging vector
typedef __attribute__((ext_vector_type(4))) int i32x4;

#define NB   32
#define TIN  1600
#define CIN  80
#define TOUT 800
#define DH   512
#define NV   1000
#define NU   200
#define TXP  1604   // xpad time rows (1 left pad + 1600 + 3 tail)
#define THP  804    // conv buffer time rows (2 pad each side)
#define EPSB 1e-3f
#define SENTI 0x7C007C00   // (inf,inf) f16 pair — impossible for |h|<1 data

// 16B coherent-point load (bypass L1+L2; the detecting load IS the data)
#define GL(d, b, o) asm volatile("global_load_dwordx4 %0, %1, off offset:" o " sc0 sc1" \
                                 : "=v"(d) : "v"(b) : "memory")

__device__ __forceinline__ float fast_tanh(float x)
{
    return 1.f - 2.f / (__expf(2.f * x) + 1.f);
}

// ---------------------------------------------------------------- init
__global__ void init_zero(float* gsum, float* gsumsq,
                          f16* Hc, f16* xpad, f16* hbufA, f16* hbufB)
{
    int tid = blockIdx.x * 256 + threadIdx.x;
    int stride = gridDim.x * 256;
    if (blockIdx.x == 0) {
        if (threadIdx.x < 80) { gsum[threadIdx.x] = 0.f; gsumsq[threadIdx.x] = 0.f; }
    }
    // sentinel-fill Hc[u][b][0:512] (dwords 0..255 of each 1024-f16 row)
    for (int i = tid; i < NU * 32 * 256; i += stride) {
        int row = i >> 8, d = i & 255;
        ((unsigned*)Hc)[(long)row * 512 + d] = SENTI;
    }
    // xpad zero rows: t'=0, 1601..1603 per b
    for (int i = tid; i < NB * 4 * CIN; i += stride) {
        int b = i / (4 * CIN), rr = (i / CIN) % 4, c = i % CIN;
        int row = (rr == 0) ? 0 : (1600 + rr);
        xpad[((long)b * TXP + row) * CIN + c] = (f16)0.f;
    }
    // hbuf zero rows: t'=0,1,802,803 per b, both buffers
    for (int i = tid; i < 2 * NB * 4 * DH; i += stride) {
        int q = i; int buf = q / (NB * 4 * DH); q %= NB * 4 * DH;
        int b = q / (4 * DH); int rr = (q / DH) % 4; int dd = q % DH;
        int row = (rr < 2) ? rr : (800 + rr);
        f16* hb = buf ? hbufB : hbufA;
        hb[((long)b * THP + row) * DH + dd] = (f16)0.f;
    }
}

// ---------------------------------------------------------------- transpose f32 -> f16 (out[c][r] = in[r][c], OOB -> 0)
__global__ void transpose_f32_f16(const float* __restrict__ in, int R, int C,
                                  f16* __restrict__ out, int outRows, int outCols)
{
    __shared__ float t[32][33];
    int c0 = blockIdx.x * 32, r0 = blockIdx.y * 32;
    int x = threadIdx.x & 31, y = threadIdx.x >> 5;
    for (int i = y; i < 32; i += 8) {
        int r = r0 + i, c = c0 + x;
        t[i][x] = (r < R && c < C) ? in[(long)r * C + c] : 0.0f;
    }
    __syncthreads();
    for (int i = y; i < 32; i += 8) {
        int orow = c0 + i, ocol = r0 + x;
        if (orow < outRows && ocol < outCols)
            out[(long)orow * outCols + ocol] = (f16)t[x][i];
    }
}

// ---------------------------------------------------------------- batchnorm
__global__ void bn_stats(const float* __restrict__ x, float* gsum, float* gsumsq)
{
    __shared__ float ls[240], ls2[240];
    const float* base = x + (long)blockIdx.x * 200 * CIN;
    int tid = threadIdx.x;
    if (tid < 240) {
        int c = tid % 80, rg = tid / 80;
        float s = 0.f, s2 = 0.f;
        for (int r = rg; r < 200; r += 3) {
            float v = base[r * CIN + c];
            s += v; s2 += v * v;
        }
        ls[tid] = s; ls2[tid] = s2;
    }
    __syncthreads();
    if (tid < 80) {
        atomicAdd(&gsum[tid],   ls[tid] + ls[tid + 80] + ls[tid + 160]);
        atomicAdd(&gsumsq[tid], ls2[tid] + ls2[tid + 80] + ls2[tid + 160]);
    }
}

__global__ void bn_apply(const float* __restrict__ x, const float* __restrict__ gsum,
                         const float* __restrict__ gsumsq, const float* __restrict__ gamma,
                         const float* __restrict__ beta, f16* __restrict__ xpad)
{
    long idx = (long)blockIdx.x * 256 + threadIdx.x;
    if (idx >= (long)NB * TIN * CIN) return;
    int c = (int)(idx % CIN);
    long bt = idx / CIN;
    int t = (int)(bt % TIN); int b = (int)(bt / TIN);
    float mean = gsum[c] * (1.f / 51200.f);
    float var  = gsumsq[c] * (1.f / 51200.f) - mean * mean;
    float sc = gamma[c] * rsqrtf(var + EPSB);
    float sh = beta[c] - mean * sc;
    xpad[((long)b * TXP + t + 1) * CIN + c] = (f16)(x[idx] * sc + sh);
}

// ---------------------------------------------------------------- generic fp16 MFMA GEMM (64x128 tile, K in chunks of 64)
template<int MODE>
__launch_bounds__(256)
__global__ void gemm16(const f16* __restrict__ Ab, long strideA, long slabA,
                       const f16* __restrict__ Bb, long strideB, long slabB,
                       int M, int N, int Kchunks,
                       const float* __restrict__ bias,
                       const f16* __restrict__ resid, long slabR,
                       f16* __restrict__ outH, long slabO,
                       float* __restrict__ outF)
{
    __shared__ f16 As[64][72];
    __shared__ f16 Bs[128][72];
    const int b = blockIdx.z;
    const f16* Abase = Ab + (long)b * slabA;
    const f16* Bbase = Bb + (long)b * slabB;
    const int m0 = blockIdx.x * 64, n0 = blockIdx.y * 128;
    const int tid = threadIdx.x;
    const int lane = tid & 63, wv = tid >> 6;
    const int lm = lane & 15, lk = lane >> 4;

    f32x4 vzero = {0.f, 0.f, 0.f, 0.f};
    f32x4 acc[4][2];
#pragma unroll
    for (int i = 0; i < 4; i++) { acc[i][0] = vzero; acc[i][1] = vzero; }

    const int srow = tid >> 3, scol = (tid & 7) * 8;

    for (int kc = 0; kc < Kchunks; kc++) {
        int kb = kc * 64;
#pragma unroll
        for (int p = 0; p < 2; p++) {
            int r = srow + p * 32;
            int m = m0 + r; if (m > M - 1) m = M - 1;
            *(us8*)&As[r][scol] = *(const us8*)(Abase + (long)m * strideA + kb + scol);
        }
#pragma unroll
        for (int p = 0; p < 4; p++) {
            int r = srow + p * 32;
            int n = n0 + r; if (n > N - 1) n = N - 1;
            *(us8*)&Bs[r][scol] = *(const us8*)(Bbase + (long)n * strideB + kb + scol);
        }
        __syncthreads();
#pragma unroll
        for (int ks = 0; ks < 2; ks++) {
            f16x8 af[4], bf[2];
#pragma unroll
            for (int mt = 0; mt < 4; mt++)
                af[mt] = *(const f16x8*)&As[mt * 16 + lm][ks * 32 + lk * 8];
#pragma unroll
            for (int nt = 0; nt < 2; nt++)
                bf[nt] = *(const f16x8*)&Bs[wv * 32 + nt * 16 + lm][ks * 32 + lk * 8];
#pragma unroll
            for (int mt = 0; mt < 4; mt++)
#pragma unroll
                for (int nt = 0; nt < 2; nt++)
                    acc[mt][nt] = __builtin_amdgcn_mfma_f32_16x16x32_f16(af[mt], bf[nt], acc[mt][nt], 0, 0, 0);
        }
        __syncthreads();
    }
#pragma unroll
    for (int mt = 0; mt < 4; mt++) {
#pragma unroll
        for (int nt = 0; nt < 2; nt++) {
            int n = n0 + wv * 32 + nt * 16 + lm;
#pragma unroll
            for (int reg = 0; reg < 4; reg++) {
                int m = m0 + mt * 16 + lk * 4 + reg;
                if (m >= M || n >= N) continue;
                float v = acc[mt][nt][reg];
                if (MODE == 0) {
                    v += bias[n]; v = v > 0.f ? v : 0.f;
                    outH[(long)b * slabO + (long)(2 + m) * DH + n] = (f16)v;
                } else if (MODE == 1) {
                    v += bias[n]; v = v > 0.f ? v : 0.f;
                    v += (float)resid[(long)b * slabR + (long)(2 + m) * DH + n];
                    outH[(long)b * slabO + (long)(2 + m) * DH + n] = (f16)v;
                } else if (MODE == 2) {
                    outF[((long)b * NU + m) * 800 + n] = v;
                } else {
                    v += bias[n];
                    int u = m >> 5, bb = m & 31;
                    outF[((long)bb * NU + u) * 1000 + n] = v;
                }
            }
        }
    }
}

// ---------------------------------------------------------------- GRU: tagged-data exchange, HW-race-safe poll.
// Hc[u] pre-filled with f16-inf sentinels (impossible for |h|<1 data). Producer:
// gate math -> LDS transpose (1 intra-CU barrier) -> fire 16B granule stores
// (sc0 sc1), NO drain, NO flags. Consumer: re-load granules (sc0 sc1), then
// pass ALL polled registers THROUGH the s_waitcnt asm as "+v" tied operands —
// every consumer (sentinel check, MFMA) now has a register dependence on a
// post-wait definition, so neither the check nor the MFMA can be scheduled
// before the loads complete (the R8/R9 NaN: rdy/MFMA raced the in-flight loads,
// since asm outputs carry no waitcnt protection from SIInsertWaitcnts).
__launch_bounds__(256, 1)
__global__ void gru_seq(const f16* __restrict__ wrecT, const float* __restrict__ gk,
                        const float* __restrict__ gbias, const int* __restrict__ ytrue,
                        f16* __restrict__ Hc)
{
    __shared__ int yl[NU * 32];                  // yl[u*32+b]
    __shared__ f16 hl[32][64];                   // this WG's 64 h-columns, all 32 rows
    const int tid = threadIdx.x;
    const int lane = tid & 63, wv = tid >> 6;
    const int w = (int)blockIdx.x;               // 0..7
    const int gw = w * 4 + wv;                   // gate-triple 0..31
    const int lm = lane & 15, lk = lane >> 4;
    const int j = gw * 16 + lm;                  // hidden column 0..511

    for (int i = tid; i < NU * 32; i += 256) {
        int b = i / NU, u = i - b * NU;
        yl[u * 32 + b] = ytrue[b * 201 + u];
    }

    // resident B-fragments for z/r/c gate columns
    f16x8 wf[3][16];
#pragma unroll
    for (int g = 0; g < 3; g++)
#pragma unroll
        for (int ks = 0; ks < 16; ks++)
            wf[g][ks] = *(const f16x8*)&wrecT[(long)(g * 512 + j) * 512 + ks * 32 + lk * 8];

    const float biz = gbias[j],        bir = gbias[512 + j],        bic = gbias[1024 + j];
    const float brz = gbias[1536 + j], brr = gbias[1536 + 512 + j], brc = gbias[1536 + 1024 + j];
    f32x4 vzero = {0.f, 0.f, 0.f, 0.f};

    __syncthreads();   // yl visible

    float hold[8];
    float nxz[8], nxr[8], nxh[8], mxz[8], mxr[8], mxh[8];
#pragma unroll
    for (int s = 0; s < 8; s++) {
        hold[s] = 0.f;
        int b = ((s >> 2) << 4) + lk * 4 + (s & 3);
        const float* gkr = gk + (long)yl[b] * 1536;        // u = 0
        nxz[s] = gkr[j]; nxr[s] = gkr[512 + j]; nxh[s] = gkr[1024 + j];
    }

    const int srow = tid >> 3, sch = tid & 7;              // cooperative-store map

    for (int u = 0; u < NU; u++) {
        f32x4 acc[3][2];
#pragma unroll
        for (int g = 0; g < 3; g++) { acc[g][0] = vzero; acc[g][1] = vzero; }

        if (u > 0) {
            // poll the 32 A-fragment granules of h[u-1] directly
            const f16* b0p = Hc + ((long)(u - 1) * 32 + lm) * 1024 + lk * 8;
            const f16* b1p = b0p + 16 * 1024;
            f16x8 a0[16], a1[16];
            while (true) {
                GL(a0[0],  b0p, "0");   GL(a0[1],  b0p, "64");  GL(a0[2],  b0p, "128"); GL(a0[3],  b0p, "192");
                GL(a0[4],  b0p, "256"); GL(a0[5],  b0p, "320"); GL(a0[6],  b0p, "384"); GL(a0[7],  b0p, "448");
                GL(a0[8],  b0p, "512"); GL(a0[9],  b0p, "576"); GL(a0[10], b0p, "640"); GL(a0[11], b0p, "704");
                GL(a0[12], b0p, "768"); GL(a0[13], b0p, "832"); GL(a0[14], b0p, "896"); GL(a0[15], b0p, "960");
                GL(a1[0],  b1p, "0");   GL(a1[1],  b1p, "64");  GL(a1[2],  b1p, "128"); GL(a1[3],  b1p, "192");
                GL(a1[4],  b1p, "256"); GL(a1[5],  b1p, "320"); GL(a1[6],  b1p, "384"); GL(a1[7],  b1p, "448");
                GL(a1[8],  b1p, "512"); GL(a1[9],  b1p, "576"); GL(a1[10], b1p, "640"); GL(a1[11], b1p, "704");
                GL(a1[12], b1p, "768"); GL(a1[13], b1p, "832"); GL(a1[14], b1p, "896"); GL(a1[15], b1p, "960");
                // Tie every polled register through the wait: values are only
                // "defined" (for SSA consumers) AFTER vmcnt(0) has executed.
                asm volatile("s_waitcnt vmcnt(0)"
                             : "+v"(a0[0]), "+v"(a0[1]), "+v"(a0[2]), "+v"(a0[3]),
                               "+v"(a0[4]), "+v"(a0[5]), "+v"(a0[6]), "+v"(a0[7])
                             :: "memory");
                asm volatile(""
                             : "+v"(a0[8]),  "+v"(a0[9]),  "+v"(a0[10]), "+v"(a0[11]),
                               "+v"(a0[12]), "+v"(a0[13]), "+v"(a0[14]), "+v"(a0[15])
                             :: "memory");
                asm volatile(""
                             : "+v"(a1[0]), "+v"(a1[1]), "+v"(a1[2]), "+v"(a1[3]),
                               "+v"(a1[4]), "+v"(a1[5]), "+v"(a1[6]), "+v"(a1[7])
                             :: "memory");
                asm volatile(""
                             : "+v"(a1[8]),  "+v"(a1[9]),  "+v"(a1[10]), "+v"(a1[11]),
                               "+v"(a1[12]), "+v"(a1[13]), "+v"(a1[14]), "+v"(a1[15])
                             :: "memory");
                unsigned rdy = 1u;
#pragma unroll
                for (int ks = 0; ks < 16; ks++) {
                    i32x4 w0 = __builtin_bit_cast(i32x4, a0[ks]);
                    i32x4 w1 = __builtin_bit_cast(i32x4, a1[ks]);
                    rdy &= (unsigned)(w0.x != SENTI) & (unsigned)(w0.y != SENTI)
                         & (unsigned)(w0.z != SENTI) & (unsigned)(w0.w != SENTI)
                         & (unsigned)(w1.x != SENTI) & (unsigned)(w1.y != SENTI)
                         & (unsigned)(w1.z != SENTI) & (unsigned)(w1.w != SENTI);
                }
                if (rdy) break;
                __builtin_amdgcn_s_sleep(1);
            }
            // gathers for this step had the whole poll to land
#pragma unroll
            for (int s = 0; s < 8; s++) { nxz[s] = mxz[s]; nxr[s] = mxr[s]; nxh[s] = mxh[s]; }
#pragma unroll
            for (int ks = 0; ks < 16; ks++) {
#pragma unroll
                for (int g = 0; g < 3; g++) {
                    acc[g][0] = __builtin_amdgcn_mfma_f32_16x16x32_f16(a0[ks], wf[g][ks], acc[g][0], 0, 0, 0);
                    acc[g][1] = __builtin_amdgcn_mfma_f32_16x16x32_f16(a1[ks], wf[g][ks], acc[g][1], 0, 0, 0);
                }
            }
        }

        // gates + state update (fp32); own h -> LDS (for cooperative store)
#pragma unroll
        for (int mt = 0; mt < 2; mt++) {
#pragma unroll
            for (int reg = 0; reg < 4; reg++) {
                int s = mt * 4 + reg;
                int b = mt * 16 + lk * 4 + reg;
                float hz = acc[0][mt][reg] + brz;
                float hr = acc[1][mt][reg] + brr;
                float hh = acc[2][mt][reg] + brc;
                float z = 1.f / (1.f + __expf(-(nxz[s] + biz + hz)));
                float r = 1.f / (1.f + __expf(-(nxr[s] + bir + hr)));
                float cd = fast_tanh(nxh[s] + bic + r * hh);
                float hnew = z * hold[s] + (1.f - z) * cd;
                hold[s] = hnew;
                hl[b][wv * 16 + lm] = (f16)hnew;
            }
        }
        __syncthreads();   // hl complete (intra-CU, ~100 cyc)

        // cooperative granule store: lane -> (row srow, chunk w*8+sch), 16B, fire
        {
            f16x8 gval = *(const f16x8*)&hl[srow][sch * 8];
            f16* gp = Hc + ((long)u * 32 + srow) * 1024 + w * 64 + sch * 8;
            asm volatile("global_store_dwordx4 %0, %1, off sc0 sc1"
                         :: "v"(gp), "v"(gval) : "memory");
        }

        // prefetch gathers for u+1 (plain loads; drain during next poll)
        if (u < NU - 1) {
#pragma unroll
            for (int s = 0; s < 8; s++) {
                int b = ((s >> 2) << 4) + lk * 4 + (s & 3);
                const float* gkr = gk + (long)yl[(u + 1) * 32 + b] * 1536;
                mxz[s] = gkr[j]; mxr[s] = gkr[512 + j]; mxh[s] = gkr[1024 + j];
            }
        }
    }
    asm volatile("s_waitcnt vmcnt(0)" ::: "memory");  // drain final stores
}

// ---------------------------------------------------------------- row softmax in place (len <= 1024)
__global__ void row_softmax(float* __restrict__ base, int len)
{
    float* s = base + (long)blockIdx.x * len;
    int tid = threadIdx.x;
    float v[4]; float mx = -1e30f;
#pragma unroll
    for (int i = 0; i < 4; i++) {
        int idx = tid + i * 256;
        v[i] = (idx < len) ? s[idx] : -1e30f;
        mx = fmaxf(mx, v[i]);
    }
#pragma unroll
    for (int off = 32; off; off >>= 1) mx = fmaxf(mx, __shfl_xor(mx, off));
    __shared__ float red[4], red2[4];
    if ((tid & 63) == 0) red[tid >> 6] = mx;
    __syncthreads();
    mx = fmaxf(fmaxf(red[0], red[1]), fmaxf(red[2], red[3]));
    float sum = 0.f;
#pragma unroll
    for (int i = 0; i < 4; i++) { v[i] = __expf(v[i] - mx); sum += v[i]; }
#pragma unroll
    for (int off = 32; off; off >>= 1) sum += __shfl_xor(sum, off);
    if ((tid & 63) == 0) red2[tid >> 6] = sum;
    __syncthreads();
    sum = red2[0] + red2[1] + red2[2] + red2[3];
    float inv = 1.f / sum;
#pragma unroll
    for (int i = 0; i < 4; i++) {
        int idx = tid + i * 256;
        if (idx < len) s[idx] = v[i] * inv;
    }
}

// ---------------------------------------------------------------- ctx: ctx[b][u][:] = alpha[b][u][:] @ enc[b], u-blocked by 16
__global__ void ctx_kernel(const float* __restrict__ alpha, const f16* __restrict__ enc,
                           f16* __restrict__ Hc)
{
    __shared__ float al[800][18];
    int b = blockIdx.x, ut = blockIdx.y;
    int u0 = ut * 16;
    int tid = threadIdx.x;
    for (int ul = 0; ul < 16; ul++) {
        int u = u0 + ul;
        if (u < NU) {
            const float* arow = alpha + ((long)b * NU + u) * 800;
            for (int t = tid; t < 800; t += 256) al[t][ul] = arow[t];
        } else {
            for (int t = tid; t < 800; t += 256) al[t][ul] = 0.f;
        }
    }
    __syncthreads();
    int d0 = tid * 2;
    float a0[16], a1[16];
#pragma unroll
    for (int i = 0; i < 16; i++) { a0[i] = 0.f; a1[i] = 0.f; }
    const f16* encb = enc + ((long)b * THP + 2) * DH + d0;
    for (int t = 0; t < 800; t++) {
        f16x2 e = *(const f16x2*)&encb[(long)t * DH];
        float f0 = (float)e.x, f1 = (float)e.y;
#pragma unroll
        for (int g = 0; g < 8; g++) {
            f32x2 ap = *(const f32x2*)&al[t][2 * g];
            a0[2 * g]     += ap.x * f0; a0[2 * g + 1] += ap.y * f0;
            a1[2 * g]     += ap.x * f1; a1[2 * g + 1] += ap.y * f1;
        }
    }
#pragma unroll
    for (int ul = 0; ul < 16; ul++) {
        int u = u0 + ul;
        if (u < NU) {
            Hc[((long)u * 32 + b) * 1024 + 512 + d0]     = (f16)a0[ul];
            Hc[((long)u * 32 + b) * 1024 + 512 + d0 + 1] = (f16)a1[ul];
        }
    }
}

// ---------------------------------------------------------------- launcher
extern "C" void kernel_launch(void* const* d_in, const int* in_sizes, int n_in,
                              void* d_out, int out_size, void* d_ws, size_t ws_size,
                              hipStream_t stream)
{
    const float* x     = (const float*)d_in[0];
    const int*   ytrue = (const int*)d_in[1];
    const float* gamma = (const float*)d_in[2];
    const float* beta  = (const float*)d_in[3];
    const float* w0    = (const float*)d_in[4];
    const float* b0    = (const float*)d_in[5];
    const float* tcrw  = (const float*)d_in[6];
    const float* tcrb  = (const float*)d_in[7];
    const float* gk    = (const float*)d_in[8];
    const float* grk   = (const float*)d_in[9];
    const float* gbias = (const float*)d_in[10];
    const float* fcw   = (const float*)d_in[11];
    const float* fcb   = (const float*)d_in[12];
    float* out = (float*)d_out;
    (void)in_sizes; (void)n_in; (void)out_size; (void)ws_size;

    char* ws = (char*)d_ws;
    size_t o = 0;
    auto alloc = [&](size_t bytes) { size_t r = o; o += (bytes + 255) & ~(size_t)255; return r; };
    f16*   xpad   = (f16*)(ws + alloc((size_t)NB * TXP * CIN * 2));
    f16*   hbufA  = (f16*)(ws + alloc((size_t)NB * THP * DH * 2));
    f16*   hbufB  = (f16*)(ws + alloc((size_t)NB * THP * DH * 2));
    f16*   Hc     = (f16*)(ws + alloc((size_t)NU * NB * 1024 * 2));
    float* scores = (float*)(ws + alloc((size_t)NB * NU * 800 * 4));
    f16*   w0T    = (f16*)(ws + alloc((size_t)512 * 448 * 2));
    f16*   tcrT   = (f16*)(ws + alloc((size_t)4 * 512 * 2560 * 2));
    f16*   wrecT  = (f16*)(ws + alloc((size_t)1536 * 512 * 2));
    f16*   fcT    = (f16*)(ws + alloc((size_t)1024 * 1024 * 2));
    float* gsum   = (float*)(ws + alloc(80 * 4));
    float* gsumsq = (float*)(ws + alloc(80 * 4));

    init_zero<<<64, 256, 0, stream>>>(gsum, gsumsq, Hc, xpad, hbufA, hbufB);
    transpose_f32_f16<<<dim3(16, 14), 256, 0, stream>>>(w0, 400, 512, w0T, 512, 448);
    for (int i = 0; i < 4; i++)
        transpose_f32_f16<<<dim3(16, 80), 256, 0, stream>>>(tcrw + (size_t)i * 2560 * 512, 2560, 512,
                                                            tcrT + (size_t)i * 512 * 2560, 512, 2560);
    transpose_f32_f16<<<dim3(48, 16), 256, 0, stream>>>(grk, 512, 1536, wrecT, 1536, 512);
    transpose_f32_f16<<<dim3(32, 32), 256, 0, stream>>>(fcw, 1024, 1000, fcT, 1024, 1024);

    bn_stats<<<256, 256, 0, stream>>>(x, gsum, gsumsq);
    bn_apply<<<16000, 256, 0, stream>>>(x, gsum, gsumsq, gamma, beta, xpad);

    // conv0: A[t][kk] = xpad_flat[160 t + kk], K padded 400->448 (zero weights)
    gemm16<0><<<dim3(13, 4, 32), 256, 0, stream>>>(xpad, 160, (long)TXP * CIN, w0T, 448, 0,
        800, 512, 7, b0, nullptr, 0, hbufA, (long)THP * DH, nullptr);

    const f16* tin = hbufA; f16* tout = hbufB;
    for (int i = 0; i < 4; i++) {
        gemm16<1><<<dim3(13, 4, 32), 256, 0, stream>>>(tin, 512, (long)THP * DH,
            tcrT + (size_t)i * 512 * 2560, 2560, 0,
            800, 512, 40, tcrb + i * 512, tin, (long)THP * DH, tout, (long)THP * DH, nullptr);
        const f16* t2 = tout; tout = (f16*)tin; tin = t2;
    }
    const f16* enc = tin;   // = hbufA after 4 swaps

    gru_seq<<<8, 256, 0, stream>>>(wrecT, gk, gbias, ytrue, Hc);

    // scores[b][u][t] = Hc[u][b][:512] . enc[b][t][:]
    gemm16<2><<<dim3(4, 7, 32), 256, 0, stream>>>(Hc, 32 * 1024, 1024, enc + 2 * DH, 512, (long)THP * DH,
        200, 800, 8, nullptr, nullptr, 0, nullptr, 0, scores);
    row_softmax<<<6400, 256, 0, stream>>>(scores, 800);
    ctx_kernel<<<dim3(32, 13), 256, 0, stream>>>(scores, enc, Hc);

    // logits[b][u][v] = Hc_row(u*32+b)[0:1024] @ fcT + fc_b  -> d_out
    gemm16<3><<<dim3(100, 8, 1), 256, 0, stream>>>(Hc, 1024, 0, fcT, 1024, 0,
        6400, 1000, 16, fcb, nullptr, 0, nullptr, 0, out);
    row_softmax<<<6400, 256, 0, stream>>>(out, 1000);
}

// Round 11
// 1859.772 us; speedup vs baseline: 1.4638x; 1.4638x over previous
//
#include <hip/hip_runtime.h>
#include <cstdint>

typedef _Float16 f16;
typedef __attribute__((ext_vector_type(2))) _Float16 f16x2;
typedef __attribute__((ext_vector_type(8))) _Float16 f16x8;
typedef __attribute__((ext_vector_type(4))) float f32x4;
typedef __attribute__((ext_vector_type(2))) float f32x2;
typedef __attribute__((ext_vector_type(8))) unsigned short us8;   // 16 B — staging vector
typedef __attribute__((ext_vector_type(4))) int i32x4;

#define NB   32
#define TIN  1600
#define CIN  80
#define TOUT 800
#define DH   512
#define NV   1000
#define NU   200
#define TXP  1604   // xpad time rows (1 left pad + 1600 + 3 tail)
#define THP  804    // conv buffer time rows (2 pad each side)
#define EPSB 1e-3f
#define EWG  248    // encoder worker blocks in the fused kernel (8+248 = 256 = #CUs)

// write-through (coherence-point) stores — R5-proven
__device__ __forceinline__ void st_sys_f16(f16* p, float v)
{
    f16 h = (f16)v;
    short s; __builtin_memcpy(&s, &h, 2);
    int si = (int)s;
    asm volatile("global_store_short %0, %1, off sc0 sc1"
                 :: "v"(p), "v"(si) : "memory");
}
__device__ __forceinline__ void st_sys_i32(int* p, int v)
{
    asm volatile("global_store_dword %0, %1, off sc0 sc1"
                 :: "v"(p), "v"(v) : "memory");
}

// R5-proven poll: 8 flag words, loads+waitcnt in ONE asm blob (race-free)
__device__ __forceinline__ void poll8(const int* fl, int target)
{
    i32x4 a, b;
    while (true) {
        asm volatile("global_load_dwordx4 %0, %2, off sc1\n\t"
                     "global_load_dwordx4 %1, %3, off sc1\n\t"
                     "s_waitcnt vmcnt(0)"
                     : "=&v"(a), "=&v"(b)
                     : "v"(fl), "v"(fl + 4)
                     : "memory");
        if (a.x == target && a.y == target && a.z == target && a.w == target &&
            b.x == target && b.y == target && b.z == target && b.w == target) break;
        __builtin_amdgcn_s_sleep(1);
    }
}

__device__ __forceinline__ float fast_tanh(float x)
{
    return 1.f - 2.f / (__expf(2.f * x) + 1.f);
}

// ---------------------------------------------------------------- init
__global__ void init_zero(float* gsum, float* gsumsq,
                          int* flags, int* lcnt, f16* xpad, f16* hbufA, f16* hbufB)
{
    int tid = blockIdx.x * 256 + threadIdx.x;
    int stride = gridDim.x * 256;
    if (blockIdx.x == 0) {
        if (threadIdx.x < 80) { gsum[threadIdx.x] = 0.f; gsumsq[threadIdx.x] = 0.f; }
        if (threadIdx.x >= 128 && threadIdx.x < 136) lcnt[threadIdx.x - 128] = 0;
    }
    for (int i = tid; i < NU * 8; i += stride) flags[i] = 0;
    // xpad zero rows: t'=0, 1601..1603 per b
    for (int i = tid; i < NB * 4 * CIN; i += stride) {
        int b = i / (4 * CIN), rr = (i / CIN) % 4, c = i % CIN;
        int row = (rr == 0) ? 0 : (1600 + rr);
        xpad[((long)b * TXP + row) * CIN + c] = (f16)0.f;
    }
    // hbuf zero rows: t'=0,1,802,803 per b, both buffers
    for (int i = tid; i < 2 * NB * 4 * DH; i += stride) {
        int q = i; int buf = q / (NB * 4 * DH); q %= NB * 4 * DH;
        int b = q / (4 * DH); int rr = (q / DH) % 4; int dd = q % DH;
        int row = (rr < 2) ? rr : (800 + rr);
        f16* hb = buf ? hbufB : hbufA;
        hb[((long)b * THP + row) * DH + dd] = (f16)0.f;
    }
}

// ---------------------------------------------------------------- transpose f32 -> f16 (out[c][r] = in[r][c], OOB -> 0)
__global__ void transpose_f32_f16(const float* __restrict__ in, int R, int C,
                                  f16* __restrict__ out, int outRows, int outCols)
{
    __shared__ float t[32][33];
    int c0 = blockIdx.x * 32, r0 = blockIdx.y * 32;
    int x = threadIdx.x & 31, y = threadIdx.x >> 5;
    for (int i = y; i < 32; i += 8) {
        int r = r0 + i, c = c0 + x;
        t[i][x] = (r < R && c < C) ? in[(long)r * C + c] : 0.0f;
    }
    __syncthreads();
    for (int i = y; i < 32; i += 8) {
        int orow = c0 + i, ocol = r0 + x;
        if (orow < outRows && ocol < outCols)
            out[(long)orow * outCols + ocol] = (f16)t[x][i];
    }
}

// ---------------------------------------------------------------- batchnorm
__global__ void bn_stats(const float* __restrict__ x, float* gsum, float* gsumsq)
{
    __shared__ float ls[240], ls2[240];
    const float* base = x + (long)blockIdx.x * 200 * CIN;
    int tid = threadIdx.x;
    if (tid < 240) {
        int c = tid % 80, rg = tid / 80;
        float s = 0.f, s2 = 0.f;
        for (int r = rg; r < 200; r += 3) {
            float v = base[r * CIN + c];
            s += v; s2 += v * v;
        }
        ls[tid] = s; ls2[tid] = s2;
    }
    __syncthreads();
    if (tid < 80) {
        atomicAdd(&gsum[tid],   ls[tid] + ls[tid + 80] + ls[tid + 160]);
        atomicAdd(&gsumsq[tid], ls2[tid] + ls2[tid + 80] + ls2[tid + 160]);
    }
}

__global__ void bn_apply(const float* __restrict__ x, const float* __restrict__ gsum,
                         const float* __restrict__ gsumsq, const float* __restrict__ gamma,
                         const float* __restrict__ beta, f16* __restrict__ xpad)
{
    long idx = (long)blockIdx.x * 256 + threadIdx.x;
    if (idx >= (long)NB * TIN * CIN) return;
    int c = (int)(idx % CIN);
    long bt = idx / CIN;
    int t = (int)(bt % TIN); int b = (int)(bt / TIN);
    float mean = gsum[c] * (1.f / 51200.f);
    float var  = gsumsq[c] * (1.f / 51200.f) - mean * mean;
    float sc = gamma[c] * rsqrtf(var + EPSB);
    float sh = beta[c] - mean * sc;
    xpad[((long)b * TXP + t + 1) * CIN + c] = (f16)(x[idx] * sc + sh);
}

// ---------------------------------------------------------------- generic fp16 MFMA GEMM (64x128 tile) — tail use only
// MODE 2: attention scores (f32)   MODE 3: fc (bias -> f32 logits in d_out)
template<int MODE>
__launch_bounds__(256)
__global__ void gemm16(const f16* __restrict__ Ab, long strideA, long slabA,
                       const f16* __restrict__ Bb, long strideB, long slabB,
                       int M, int N, int Kchunks,
                       const float* __restrict__ bias,
                       float* __restrict__ outF)
{
    __shared__ f16 As[64][72];
    __shared__ f16 Bs[128][72];
    const int b = blockIdx.z;
    const f16* Abase = Ab + (long)b * slabA;
    const f16* Bbase = Bb + (long)b * slabB;
    const int m0 = blockIdx.x * 64, n0 = blockIdx.y * 128;
    const int tid = threadIdx.x;
    const int lane = tid & 63, wv = tid >> 6;
    const int lm = lane & 15, lk = lane >> 4;

    f32x4 vzero = {0.f, 0.f, 0.f, 0.f};
    f32x4 acc[4][2];
#pragma unroll
    for (int i = 0; i < 4; i++) { acc[i][0] = vzero; acc[i][1] = vzero; }

    const int srow = tid >> 3, scol = (tid & 7) * 8;

    for (int kc = 0; kc < Kchunks; kc++) {
        int kb = kc * 64;
#pragma unroll
        for (int p = 0; p < 2; p++) {
            int r = srow + p * 32;
            int m = m0 + r; if (m > M - 1) m = M - 1;
            *(us8*)&As[r][scol] = *(const us8*)(Abase + (long)m * strideA + kb + scol);
        }
#pragma unroll
        for (int p = 0; p < 4; p++) {
            int r = srow + p * 32;
            int n = n0 + r; if (n > N - 1) n = N - 1;
            *(us8*)&Bs[r][scol] = *(const us8*)(Bbase + (long)n * strideB + kb + scol);
        }
        __syncthreads();
#pragma unroll
        for (int ks = 0; ks < 2; ks++) {
            f16x8 af[4], bf[2];
#pragma unroll
            for (int mt = 0; mt < 4; mt++)
                af[mt] = *(const f16x8*)&As[mt * 16 + lm][ks * 32 + lk * 8];
#pragma unroll
            for (int nt = 0; nt < 2; nt++)
                bf[nt] = *(const f16x8*)&Bs[wv * 32 + nt * 16 + lm][ks * 32 + lk * 8];
#pragma unroll
            for (int mt = 0; mt < 4; mt++)
#pragma unroll
                for (int nt = 0; nt < 2; nt++)
                    acc[mt][nt] = __builtin_amdgcn_mfma_f32_16x16x32_f16(af[mt], bf[nt], acc[mt][nt], 0, 0, 0);
        }
        __syncthreads();
    }
#pragma unroll
    for (int mt = 0; mt < 4; mt++) {
#pragma unroll
        for (int nt = 0; nt < 2; nt++) {
            int n = n0 + wv * 32 + nt * 16 + lm;
#pragma unroll
            for (int reg = 0; reg < 4; reg++) {
                int m = m0 + mt * 16 + lk * 4 + reg;
                if (m >= M || n >= N) continue;
                float v = acc[mt][nt][reg];
                if (MODE == 2) {
                    outF[((long)b * NU + m) * 800 + n] = v;
                } else {
                    v += bias[n];
                    int u = m >> 5, bb = m & 31;
                    outF[((long)bb * NU + u) * 1000 + n] = v;
                }
            }
        }
    }
}

// ---------------------------------------------------------------- encoder layer worker (inside fused kernel)
// One layer = 1664 tiles (32 batches x 13 Mtiles x 4 Ntiles), M=800, N=512.
__device__ void enc_layer(int eb, int tid,
                          const f16* __restrict__ Ab, long strideA, long slabA,
                          const f16* __restrict__ Bb, long strideB,
                          int Kchunks, const float* __restrict__ bias,
                          const f16* __restrict__ resid, f16* __restrict__ outH,
                          long slabRO, f16 As[][72], f16 Bs[][72])
{
    const int lane = tid & 63, wv = tid >> 6;
    const int lm = lane & 15, lk = lane >> 4;
    const int srow = tid >> 3, scol = (tid & 7) * 8;
    f32x4 vzero = {0.f, 0.f, 0.f, 0.f};

    for (int t = eb; t < 1664; t += EWG) {
        int b = t / 52, rem = t - b * 52;
        int m0 = (rem >> 2) * 64, n0 = (rem & 3) * 128;
        const f16* Abase = Ab + (long)b * slabA;

        f32x4 acc[4][2];
#pragma unroll
        for (int i = 0; i < 4; i++) { acc[i][0] = vzero; acc[i][1] = vzero; }

        for (int kc = 0; kc < Kchunks; kc++) {
            int kb = kc * 64;
#pragma unroll
            for (int p = 0; p < 2; p++) {
                int r = srow + p * 32;
                int m = m0 + r; if (m > 799) m = 799;
                *(us8*)&As[r][scol] = *(const us8*)(Abase + (long)m * strideA + kb + scol);
            }
#pragma unroll
            for (int p = 0; p < 4; p++) {
                int r = srow + p * 32;
                *(us8*)&Bs[r][scol] = *(const us8*)(Bb + (long)(n0 + r) * strideB + kb + scol);
            }
            __syncthreads();
#pragma unroll
            for (int ks = 0; ks < 2; ks++) {
                f16x8 af[4], bf[2];
#pragma unroll
                for (int mt = 0; mt < 4; mt++)
                    af[mt] = *(const f16x8*)&As[mt * 16 + lm][ks * 32 + lk * 8];
#pragma unroll
                for (int nt = 0; nt < 2; nt++)
                    bf[nt] = *(const f16x8*)&Bs[wv * 32 + nt * 16 + lm][ks * 32 + lk * 8];
#pragma unroll
                for (int mt = 0; mt < 4; mt++)
#pragma unroll
                    for (int nt = 0; nt < 2; nt++)
                        acc[mt][nt] = __builtin_amdgcn_mfma_f32_16x16x32_f16(af[mt], bf[nt], acc[mt][nt], 0, 0, 0);
            }
            __syncthreads();
        }
#pragma unroll
        for (int mt = 0; mt < 4; mt++) {
#pragma unroll
            for (int nt = 0; nt < 2; nt++) {
                int n = n0 + wv * 32 + nt * 16 + lm;
#pragma unroll
                for (int reg = 0; reg < 4; reg++) {
                    int m = m0 + mt * 16 + lk * 4 + reg;
                    if (m >= 800) continue;
                    float v = acc[mt][nt][reg] + bias[n];
                    v = v > 0.f ? v : 0.f;
                    if (resid) v += (float)resid[(long)b * slabRO + (long)(2 + m) * DH + n];
                    outH[(long)b * slabRO + (long)(2 + m) * DH + n] = (f16)v;
                }
            }
        }
    }
}

// ---------------------------------------------------------------- fused: blocks 0..7 = GRU (R5 protocol verbatim),
// blocks 8..255 = persistent encoder workers (conv0 + 4 TCR layers, release/
// acquire counter barrier between layers — R3-proven cross-XCD pattern).
__launch_bounds__(256, 1)
__global__ void enc_gru(const f16* __restrict__ wrecT, const float* __restrict__ gk,
                        const float* __restrict__ gbias, const int* __restrict__ ytrue,
                        f16* __restrict__ Hc, int* __restrict__ flags,
                        const f16* __restrict__ xpad, const f16* __restrict__ w0T,
                        const float* __restrict__ b0, const f16* __restrict__ tcrT,
                        const float* __restrict__ tcrb,
                        f16* __restrict__ hbufA, f16* __restrict__ hbufB,
                        int* __restrict__ lcnt)
{
    const int tid = threadIdx.x;

    if (blockIdx.x < 8) {
        // ==================== GRU (R5 verbatim) ====================
        __shared__ int yl[NU * 32];
        const int lane = tid & 63, wv = tid >> 6;
        const int gw = (int)blockIdx.x * 4 + wv;
        const int lm = lane & 15, lk = lane >> 4;
        const int j = gw * 16 + lm;

        for (int i = tid; i < NU * 32; i += 256) {
            int b = i / NU, u = i - b * NU;
            yl[u * 32 + b] = ytrue[b * 201 + u];
        }

        f16x8 wf[3][16];
#pragma unroll
        for (int g = 0; g < 3; g++)
#pragma unroll
            for (int ks = 0; ks < 16; ks++)
                wf[g][ks] = *(const f16x8*)&wrecT[(long)(g * 512 + j) * 512 + ks * 32 + lk * 8];

        const float biz = gbias[j],        bir = gbias[512 + j],        bic = gbias[1024 + j];
        const float brz = gbias[1536 + j], brr = gbias[1536 + 512 + j], brc = gbias[1536 + 1024 + j];
        f32x4 vzero = {0.f, 0.f, 0.f, 0.f};

        __syncthreads();

        float hold[8];
        float nxz[8], nxr[8], nxh[8], mxz[8], mxr[8], mxh[8];
#pragma unroll
        for (int s = 0; s < 8; s++) {
            hold[s] = 0.f;
            int b = ((s >> 2) << 4) + lk * 4 + (s & 3);
            const float* gkr = gk + (long)yl[b] * 1536;
            nxz[s] = gkr[j]; nxr[s] = gkr[512 + j]; nxh[s] = gkr[1024 + j];
        }

        for (int u = 0; u < NU; u++) {
            int up = (u < NU - 1) ? u + 1 : u;
#pragma unroll
            for (int s = 0; s < 8; s++) {
                int b = ((s >> 2) << 4) + lk * 4 + (s & 3);
                const float* gkr = gk + (long)yl[up * 32 + b] * 1536;
                mxz[s] = gkr[j]; mxr[s] = gkr[512 + j]; mxh[s] = gkr[1024 + j];
            }

            f32x4 acc[3][2];
#pragma unroll
            for (int g = 0; g < 3; g++) { acc[g][0] = vzero; acc[g][1] = vzero; }

            if (u > 0) {
                poll8(flags + (u - 1) * 8, u);
                const f16* hrow = Hc + (long)(u - 1) * 32 * 1024 + lk * 8;
#pragma unroll
                for (int ks = 0; ks < 16; ks++) {
                    f16x8 a0 = *(const f16x8*)(hrow + (long)lm * 1024 + ks * 32);
                    f16x8 a1 = *(const f16x8*)(hrow + (long)(16 + lm) * 1024 + ks * 32);
#pragma unroll
                    for (int g = 0; g < 3; g++) {
                        acc[g][0] = __builtin_amdgcn_mfma_f32_16x16x32_f16(a0, wf[g][ks], acc[g][0], 0, 0, 0);
                        acc[g][1] = __builtin_amdgcn_mfma_f32_16x16x32_f16(a1, wf[g][ks], acc[g][1], 0, 0, 0);
                    }
                }
            }

#pragma unroll
            for (int mt = 0; mt < 2; mt++) {
#pragma unroll
                for (int reg = 0; reg < 4; reg++) {
                    int s = mt * 4 + reg;
                    int b = mt * 16 + lk * 4 + reg;
                    float hz = acc[0][mt][reg] + brz;
                    float hr = acc[1][mt][reg] + brr;
                    float hh = acc[2][mt][reg] + brc;
                    float z = 1.f / (1.f + __expf(-(nxz[s] + biz + hz)));
                    float r = 1.f / (1.f + __expf(-(nxr[s] + bir + hr)));
                    float cd = fast_tanh(nxh[s] + bic + r * hh);
                    float hnew = z * hold[s] + (1.f - z) * cd;
                    hold[s] = hnew;
                    st_sys_f16(&Hc[((long)u * 32 + b) * 1024 + j], hnew);
                }
            }
#pragma unroll
            for (int s = 0; s < 8; s++) { nxz[s] = mxz[s]; nxr[s] = mxr[s]; nxh[s] = mxh[s]; }

            if (u < NU - 1) {
                asm volatile("s_waitcnt vmcnt(0)" ::: "memory");
                __syncthreads();
                if (tid == 0) st_sys_i32(&flags[u * 8 + (int)blockIdx.x], u + 1);
            }
        }
        asm volatile("s_waitcnt vmcnt(0)" ::: "memory");
        return;
    }

    // ==================== encoder workers ====================
    __shared__ f16 As[64][72];
    __shared__ f16 Bs[128][72];
    const int eb = (int)blockIdx.x - 8;

    // layer 0: conv0
    enc_layer(eb, tid, xpad, 160, (long)TXP * CIN, w0T, 448, 7, b0,
              nullptr, hbufA, (long)THP * DH, As, Bs);

    const f16* tin = hbufA; f16* tout = hbufB;
    for (int L = 0; L < 4; L++) {
        // barrier: publish layer L-output (wbl2 via release), wait all, invalidate (acquire)
        __syncthreads();
        if (tid == 0) {
            __hip_atomic_fetch_add(&lcnt[L], 1, __ATOMIC_RELEASE, __HIP_MEMORY_SCOPE_AGENT);
            while (__hip_atomic_load(&lcnt[L], __ATOMIC_RELAXED, __HIP_MEMORY_SCOPE_AGENT) < EWG)
                __builtin_amdgcn_s_sleep(8);
            (void)__hip_atomic_load(&lcnt[L], __ATOMIC_ACQUIRE, __HIP_MEMORY_SCOPE_AGENT);
        }
        __syncthreads();

        enc_layer(eb, tid, tin, 512, (long)THP * DH, tcrT + (size_t)L * 512 * 2560, 2560,
                  40, tcrb + L * 512, tin, tout, (long)THP * DH, As, Bs);
        const f16* t2 = tout; tout = (f16*)tin; tin = t2;
    }
    // final output in hbufA; kernel-end flush publishes it to later dispatches
}

// ---------------------------------------------------------------- row softmax in place (len <= 1024)
__global__ void row_softmax(float* __restrict__ base, int len)
{
    float* s = base + (long)blockIdx.x * len;
    int tid = threadIdx.x;
    float v[4]; float mx = -1e30f;
#pragma unroll
    for (int i = 0; i < 4; i++) {
        int idx = tid + i * 256;
        v[i] = (idx < len) ? s[idx] : -1e30f;
        mx = fmaxf(mx, v[i]);
    }
#pragma unroll
    for (int off = 32; off; off >>= 1) mx = fmaxf(mx, __shfl_xor(mx, off));
    __shared__ float red[4], red2[4];
    if ((tid & 63) == 0) red[tid >> 6] = mx;
    __syncthreads();
    mx = fmaxf(fmaxf(red[0], red[1]), fmaxf(red[2], red[3]));
    float sum = 0.f;
#pragma unroll
    for (int i = 0; i < 4; i++) { v[i] = __expf(v[i] - mx); sum += v[i]; }
#pragma unroll
    for (int off = 32; off; off >>= 1) sum += __shfl_xor(sum, off);
    if ((tid & 63) == 0) red2[tid >> 6] = sum;
    __syncthreads();
    sum = red2[0] + red2[1] + red2[2] + red2[3];
    float inv = 1.f / sum;
#pragma unroll
    for (int i = 0; i < 4; i++) {
        int idx = tid + i * 256;
        if (idx < len) s[idx] = v[i] * inv;
    }
}

// ---------------------------------------------------------------- ctx: ctx[b][u][:] = alpha[b][u][:] @ enc[b], u-blocked by 16
__global__ void ctx_kernel(const float* __restrict__ alpha, const f16* __restrict__ enc,
                           f16* __restrict__ Hc)
{
    __shared__ float al[800][18];
    int b = blockIdx.x, ut = blockIdx.y;
    int u0 = ut * 16;
    int tid = threadIdx.x;
    for (int ul = 0; ul < 16; ul++) {
        int u = u0 + ul;
        if (u < NU) {
            const float* arow = alpha + ((long)b * NU + u) * 800;
            for (int t = tid; t < 800; t += 256) al[t][ul] = arow[t];
        } else {
            for (int t = tid; t < 800; t += 256) al[t][ul] = 0.f;
        }
    }
    __syncthreads();
    int d0 = tid * 2;
    float a0[16], a1[16];
#pragma unroll
    for (int i = 0; i < 16; i++) { a0[i] = 0.f; a1[i] = 0.f; }
    const f16* encb = enc + ((long)b * THP + 2) * DH + d0;
    for (int t = 0; t < 800; t++) {
        f16x2 e = *(const f16x2*)&encb[(long)t * DH];
        float f0 = (float)e.x, f1 = (float)e.y;
#pragma unroll
        for (int g = 0; g < 8; g++) {
            f32x2 ap = *(const f32x2*)&al[t][2 * g];
            a0[2 * g]     += ap.x * f0; a0[2 * g + 1] += ap.y * f0;
            a1[2 * g]     += ap.x * f1; a1[2 * g + 1] += ap.y * f1;
        }
    }
#pragma unroll
    for (int ul = 0; ul < 16; ul++) {
        int u = u0 + ul;
        if (u < NU) {
            Hc[((long)u * 32 + b) * 1024 + 512 + d0]     = (f16)a0[ul];
            Hc[((long)u * 32 + b) * 1024 + 512 + d0 + 1] = (f16)a1[ul];
        }
    }
}

// ---------------------------------------------------------------- launcher
extern "C" void kernel_launch(void* const* d_in, const int* in_sizes, int n_in,
                              void* d_out, int out_size, void* d_ws, size_t ws_size,
                              hipStream_t stream)
{
    const float* x     = (const float*)d_in[0];
    const int*   ytrue = (const int*)d_in[1];
    const float* gamma = (const float*)d_in[2];
    const float* beta  = (const float*)d_in[3];
    const float* w0    = (const float*)d_in[4];
    const float* b0    = (const float*)d_in[5];
    const float* tcrw  = (const float*)d_in[6];
    const float* tcrb  = (const float*)d_in[7];
    const float* gk    = (const float*)d_in[8];
    const float* grk   = (const float*)d_in[9];
    const float* gbias = (const float*)d_in[10];
    const float* fcw   = (const float*)d_in[11];
    const float* fcb   = (const float*)d_in[12];
    float* out = (float*)d_out;
    (void)in_sizes; (void)n_in; (void)out_size; (void)ws_size;

    char* ws = (char*)d_ws;
    size_t o = 0;
    auto alloc = [&](size_t bytes) { size_t r = o; o += (bytes + 255) & ~(size_t)255; return r; };
    f16*   xpad   = (f16*)(ws + alloc((size_t)NB * TXP * CIN * 2));
    f16*   hbufA  = (f16*)(ws + alloc((size_t)NB * THP * DH * 2));
    f16*   hbufB  = (f16*)(ws + alloc((size_t)NB * THP * DH * 2));
    f16*   Hc     = (f16*)(ws + alloc((size_t)NU * NB * 1024 * 2));
    float* scores = (float*)(ws + alloc((size_t)NB * NU * 800 * 4));
    f16*   w0T    = (f16*)(ws + alloc((size_t)512 * 448 * 2));
    f16*   tcrT   = (f16*)(ws + alloc((size_t)4 * 512 * 2560 * 2));
    f16*   wrecT  = (f16*)(ws + alloc((size_t)1536 * 512 * 2));
    f16*   fcT    = (f16*)(ws + alloc((size_t)1024 * 1024 * 2));
    float* gsum   = (float*)(ws + alloc(80 * 4));
    float* gsumsq = (float*)(ws + alloc(80 * 4));
    int*   flags  = (int*)(ws + alloc(NU * 8 * 4));
    int*   lcnt   = (int*)(ws + alloc(64));

    init_zero<<<64, 256, 0, stream>>>(gsum, gsumsq, flags, lcnt, xpad, hbufA, hbufB);
    transpose_f32_f16<<<dim3(16, 14), 256, 0, stream>>>(w0, 400, 512, w0T, 512, 448);
    for (int i = 0; i < 4; i++)
        transpose_f32_f16<<<dim3(16, 80), 256, 0, stream>>>(tcrw + (size_t)i * 2560 * 512, 2560, 512,
                                                            tcrT + (size_t)i * 512 * 2560, 512, 2560);
    transpose_f32_f16<<<dim3(48, 16), 256, 0, stream>>>(grk, 512, 1536, wrecT, 1536, 512);
    transpose_f32_f16<<<dim3(32, 32), 256, 0, stream>>>(fcw, 1024, 1000, fcT, 1024, 1024);

    bn_stats<<<256, 256, 0, stream>>>(x, gsum, gsumsq);
    bn_apply<<<16000, 256, 0, stream>>>(x, gsum, gsumsq, gamma, beta, xpad);

    // fused: GRU (blocks 0..7) + encoder conv chain (blocks 8..255)
    enc_gru<<<8 + EWG, 256, 0, stream>>>(wrecT, gk, gbias, ytrue, Hc, flags,
                                         xpad, w0T, b0, tcrT, tcrb, hbufA, hbufB, lcnt);
    const f16* enc = hbufA;   // after 4 ping-pong swaps

    // scores[b][u][t] = Hc[u][b][:512] . enc[b][t][:]
    gemm16<2><<<dim3(4, 7, 32), 256, 0, stream>>>(Hc, 32 * 1024, 1024, enc + 2 * DH, 512, (long)THP * DH,
        200, 800, 8, nullptr, scores);
    row_softmax<<<6400, 256, 0, stream>>>(scores, 800);
    ctx_kernel<<<dim3(32, 13), 256, 0, stream>>>(scores, enc, Hc);

    // logits[b][u][v] = Hc_row(u*32+b)[0:1024] @ fcT + fc_b  -> d_out
    gemm16<3><<<dim3(100, 8, 1), 256, 0, stream>>>(Hc, 1024, 0, fcT, 1024, 0,
        6400, 1000, 16, fcb, out);
    row_softmax<<<6400, 256, 0, stream>>>(out, 1000);
}